// Round 11
// baseline (242.905 us; speedup 1.0000x reference)
//
#include <hip/hip_runtime.h>
#include <hip/hip_fp16.h>
#include <stdint.h>

#define FP8_MAX_V 448.0f
#define BM 256
#define BN 256
#define BKB 128  // K-bytes per tile step (fp8 => 128 elements); LDS row = 128 B

typedef float floatx4 __attribute__((ext_vector_type(4)));
typedef int intx4 __attribute__((ext_vector_type(4)));
typedef int intx8 __attribute__((ext_vector_type(8)));

// asm wait/barrier with full compiler fencing (rule #18).
#define WAITVM(n)                                              \
  do {                                                         \
    asm volatile("s_waitcnt vmcnt(" #n ")" ::: "memory");      \
    __builtin_amdgcn_sched_barrier(0);                         \
  } while (0)
#define BARRIER()                                              \
  do {                                                         \
    __builtin_amdgcn_sched_barrier(0);                         \
    __builtin_amdgcn_s_barrier();                              \
    __builtin_amdgcn_sched_barrier(0);                         \
  } while (0)

// Deterministic bf16 round-to-nearest-even of an fp32 value, returned widened to fp32.
__device__ __forceinline__ float bf16_rne(float v) {
  uint32_t u = __float_as_uint(v);
  u = (u + 0x7fffu + ((u >> 16) & 1u)) & 0xffff0000u;
  return __uint_as_float(u);
}

// Pack 4 fp32 (already clipped to +-448) into 4 OCP e4m3fn bytes via HW RNE cvt.
__device__ __forceinline__ uint32_t pack4_fp8(float a, float b, float c, float d) {
  int p = 0;
  p = __builtin_amdgcn_cvt_pk_fp8_f32(a, b, p, false);  // bytes 0..1
  p = __builtin_amdgcn_cvt_pk_fp8_f32(c, d, p, true);   // bytes 2..3
  return (uint32_t)p;
}

__device__ __forceinline__ void gload_lds16(const uint8_t* g, uint8_t* l) {
  __builtin_amdgcn_global_load_lds(
      (const __attribute__((address_space(1))) uint32_t*)g,
      (__attribute__((address_space(3))) uint32_t*)l,
      16, 0, 0);
}

// Fused per-row quantization for BOTH x (blocks 0..M-1) and w (blocks M..M+N-1):
// amax over K -> scale -> fp8. Weight path fp16-round-trips the scale (matches
// reference's scale.astype(fp16).astype(fp32)).
__global__ __launch_bounds__(256) void quant_all_kernel(
    const float* __restrict__ x, const float* __restrict__ w,
    uint8_t* __restrict__ x8, uint8_t* __restrict__ w8,
    float* __restrict__ asc, float* __restrict__ wsc, int M, int K) {
  const int blk = blockIdx.x;
  const bool isW = blk >= M;
  const int row = isW ? (blk - M) : blk;
  const float* rp = (isW ? w : x) + (size_t)row * K;
  uint8_t* out8 = (isW ? w8 : x8) + (size_t)row * K;
  float* scp = (isW ? wsc : asc) + row;
  const int tid = threadIdx.x;

  // K = 4096: 16 floats/thread as 4x float4, coalesced (stride-256 float4s).
  float4 v[4];
  float amax = 0.f;
#pragma unroll
  for (int i = 0; i < 4; ++i) {
    v[i] = ((const float4*)rp)[i * 256 + tid];
    amax = fmaxf(amax, fmaxf(fmaxf(fabsf(v[i].x), fabsf(v[i].y)),
                             fmaxf(fabsf(v[i].z), fabsf(v[i].w))));
  }
#pragma unroll
  for (int off = 32; off; off >>= 1) amax = fmaxf(amax, __shfl_xor(amax, off));
  __shared__ float red[4];
  if ((tid & 63) == 0) red[tid >> 6] = amax;
  __syncthreads();
  amax = fmaxf(fmaxf(red[0], red[1]), fmaxf(red[2], red[3]));

  float scale = fmaxf(amax / FP8_MAX_V, 1e-6f);
  if (isW) scale = __half2float(__float2half(scale));  // RNE fp16 round-trip
  if (tid == 0) *scp = scale;

  uint32_t* op = (uint32_t*)out8;
#pragma unroll
  for (int i = 0; i < 4; ++i) {
    // true fp32 division (correctly rounded) to match numpy's x / scale
    float qa = fminf(fmaxf(v[i].x / scale, -FP8_MAX_V), FP8_MAX_V);
    float qb = fminf(fmaxf(v[i].y / scale, -FP8_MAX_V), FP8_MAX_V);
    float qc = fminf(fmaxf(v[i].z / scale, -FP8_MAX_V), FP8_MAX_V);
    float qd = fminf(fmaxf(v[i].w / scale, -FP8_MAX_V), FP8_MAX_V);
    op[i * 256 + tid] = pack4_fp8(qa, qb, qc, qd);
  }
}

// C[t,o] = sum_k A8[t,k]*B8[o,k]  (both K-major), scaled + bias + bf16 round.
// m201-style phase-interleaved template, fp8-MX port with the PROVEN 128B-row
// swizzle (r5's failure cause was the 64B-row variant):
//   256x256 tile, 512 thr = 8 waves (2M x 4N), wave-tile 128x64 = 8x4 frags
//   of mfma_scale_f32_16x16x128_f8f6f4 with UNIT scales (e8m0 0x7F = 1.0).
//   Wave-tile 128x64 cuts LDS bytes/FLOP 1/64 -> 1/85 (LDS-pipe ~= matrix).
// Per K-tile, TWO phases (each fragment ds_read exactly once):
//   ph0: 16 ds_read_b128 (all 4 B-frags + A-half 0) || stage A(t+1) ->
//        BARRIER -> setprio(1) 16 MFMA setprio(0) -> BARRIER
//   ph1:  8 ds_read_b128 (A-half 1) || stage B(t+1) ->
//        BARRIER -> setprio(1) 16 MFMA setprio(0) -> [head barrier of t+1]
// The phase split gives the CU scheduler different-phase waves so the LDS
// and matrix pipes overlap instead of alternating (T3 mechanism; r7/r10's
// 2-barrier lockstep measured as the serial SUM of the two pipes).
// Tile-head WAITVM(0): tile t's 8 stage-loads were issued ~2 phases
// (~1000 cyc) earlier -> drain is free. Race-free: As[s]/Bs[s] rewritten
// only after the barrier ending their reads (ds completion is forced by the
// consuming MFMAs' lgkm before each wave reaches that barrier).
//
// LDS swizzle (T2, rule #21 both-sides): 16B chunk c16 within each 128B row
// XOR'd with (row&7); linear LDS dest (gload_lds) + pre-swizzled global
// source + swizzled read (fragment = chunks {2*hi, 2*hi+1} ^ (fr&7)).
// Measured at the 4 cyc/read b128 floor.
__global__ __launch_bounds__(512, 2) void gemm_fp8_kernel(
    const uint8_t* __restrict__ A8, const uint8_t* __restrict__ B8,
    const float* __restrict__ asc, const float* __restrict__ wsc,
    const float* __restrict__ bias, float* __restrict__ out,
    int M, int N, int K) {
  __shared__ __align__(16) uint8_t As[2][BM * BKB];  // 2 x 32 KB
  __shared__ __align__(16) uint8_t Bs[2][BN * BKB];  // 2 x 32 KB

  const int tid = threadIdx.x;
  const int lane = tid & 63;
  const int wid = tid >> 6;
  const int wr = wid >> 2;  // 0..1 (M dimension, 128 rows)
  const int wc = wid & 3;   // 0..3 (N dimension, 64 cols)

  const int ntn = N / BN;
  const int bm = blockIdx.x / ntn;
  const int bn = blockIdx.x % ntn;

  floatx4 acc[8][4] = {};

  // Staging: thread tid -> LDS linear offset tid*16 (row=tid>>3, c16=tid&7),
  // global source chunk = (tid&7) ^ (row&7). Row stride 64 between the 4
  // calls preserves (row&7), so one source offset serves all calls.
  const int srow = tid >> 3;                      // 0..63
  const int sc_log = (tid & 7) ^ (srow & 7);      // pre-swizzled source chunk
  const uint8_t* gA = A8 + (size_t)(bm * BM + srow) * K + sc_log * 16;
  const uint8_t* gB = B8 + (size_t)(bn * BN + srow) * K + sc_log * 16;
  const size_t rstep = (size_t)64 * K;

  const int fr = lane & 15;        // fragment row/col within 16
  const int hi = lane >> 4;        // 0..3: K-block of 32 elems within the 128-tile
  const int fsw = fr & 7;          // read-side swizzle key
  // Lane's 32B fragment = chunks {2*hi, 2*hi+1}, each XOR-swizzled.
  const int cls = ((2 * hi) ^ fsw) * 16;      // low 16B chunk byte offset
  const int chs = ((2 * hi + 1) ^ fsw) * 16;  // high 16B chunk byte offset

  auto stageA = [&](int buf, int k0) {
    uint8_t* lA = As[buf] + tid * 16;
#pragma unroll
    for (int i = 0; i < 4; ++i) gload_lds16(gA + i * rstep + k0, lA + i * 8192);
  };
  auto stageB = [&](int buf, int k0) {
    uint8_t* lB = Bs[buf] + tid * 16;
#pragma unroll
    for (int i = 0; i < 4; ++i) gload_lds16(gB + i * rstep + k0, lB + i * 8192);
  };

  auto loadA = [&](intx8* a, int buf, int mh) {
#pragma unroll
    for (int m = 0; m < 4; ++m) {
      const uint8_t* p = As[buf] + (size_t)(wr * 128 + (mh * 4 + m) * 16 + fr) * BKB;
      intx4 lo = *(const intx4*)(p + cls);
      intx4 hh = *(const intx4*)(p + chs);
      a[m] = (intx8){lo.x, lo.y, lo.z, lo.w, hh.x, hh.y, hh.z, hh.w};
    }
  };
  auto loadB = [&](intx8* b, int buf) {
#pragma unroll
    for (int n = 0; n < 4; ++n) {
      const uint8_t* p = Bs[buf] + (size_t)(wc * 64 + n * 16 + fr) * BKB;
      intx4 lo = *(const intx4*)(p + cls);
      intx4 hh = *(const intx4*)(p + chs);
      b[n] = (intx8){lo.x, lo.y, lo.z, lo.w, hh.x, hh.y, hh.z, hh.w};
    }
  };

  const int NT = K / BKB;  // 32
  stageA(0, 0);
  stageB(0, 0);  // 8 loads in flight

  for (int t = 0; t < NT; ++t) {
    const int cur = t & 1, nxt = cur ^ 1;
    WAITVM(0);   // tile t's 8 loads, issued ~2 phases ago -> near-free drain
    BARRIER();   // all waves' tile-t data resident; slots [nxt] free of readers

    // ---- phase 0: B-frags + A-half 0; stage A(t+1)
    intx8 a[4], b[4];
    loadB(b, cur);
    loadA(a, cur, 0);
    if (t + 1 < NT) stageA(nxt, (t + 1) * BKB);
    BARRIER();
    __builtin_amdgcn_s_setprio(1);
#pragma unroll
    for (int m = 0; m < 4; ++m)
#pragma unroll
      for (int n = 0; n < 4; ++n)
        // cbsz=0 (A=fp8 e4m3), blgp=0 (B=fp8 e4m3), scales = e8m0 0x7F = 1.0
        acc[m][n] = __builtin_amdgcn_mfma_scale_f32_16x16x128_f8f6f4(
            a[m], b[n], acc[m][n], 0, 0, 0, 0x7F7F7F7F, 0, 0x7F7F7F7F);
    __builtin_amdgcn_s_setprio(0);
    BARRIER();

    // ---- phase 1: A-half 1 (B-frags reused in regs); stage B(t+1)
    loadA(a, cur, 1);
    if (t + 1 < NT) stageB(nxt, (t + 1) * BKB);
    BARRIER();
    __builtin_amdgcn_s_setprio(1);
#pragma unroll
    for (int m = 0; m < 4; ++m)
#pragma unroll
      for (int n = 0; n < 4; ++n)
        acc[4 + m][n] = __builtin_amdgcn_mfma_scale_f32_16x16x128_f8f6f4(
            a[m], b[n], acc[4 + m][n], 0, 0, 0, 0x7F7F7F7F, 0, 0x7F7F7F7F);
    __builtin_amdgcn_s_setprio(0);
    // tail barrier folded into next iteration's head WAITVM+BARRIER
  }

  // Epilogue: C/D 16x16 layout col=lane&15, row=(lane>>4)*4+r (dtype-independent;
  // f8f6f4-scaled C/D layout is shape-determined per m121-m128).
  const int rbase = bm * BM + wr * 128;
  const int cbase = bn * BN + wc * 64;
#pragma unroll
  for (int n = 0; n < 4; ++n) {
    const int col = cbase + n * 16 + fr;
    const float wv = wsc[col];
    const float bb = bf16_rne(bias[col]);  // bias.astype(bf16).astype(f32)
#pragma unroll
    for (int m = 0; m < 8; ++m) {
      const int r0 = rbase + m * 16 + hi * 4;
#pragma unroll
      for (int r = 0; r < 4; ++r) {
        const int row = r0 + r;
        // reference order: (acc * act_scale) * w_scale + bias_bf16, then bf16 RNE
        float v = (acc[m][n][r] * asc[row]) * wv + bb;
        out[(size_t)row * N + col] = bf16_rne(v);
      }
    }
  }
}

extern "C" void kernel_launch(void* const* d_in, const int* in_sizes, int n_in,
                              void* d_out, int out_size, void* d_ws, size_t ws_size,
                              hipStream_t stream) {
  const float* x = (const float*)d_in[0];     // [B,S,K] f32
  const float* w = (const float*)d_in[1];     // [N,K] f32
  const float* bias = (const float*)d_in[2];  // [N] f32
  float* out = (float*)d_out;                 // [M,N] f32 (bf16-rounded values)

  const int N = in_sizes[2];             // 4096 (D_OUT)
  const int K = in_sizes[1] / N;         // 4096 (D_IN)
  const int M = in_sizes[0] / K;         // 8192 tokens

  uint8_t* x8 = (uint8_t*)d_ws;                    // M*K bytes
  uint8_t* w8 = x8 + (size_t)M * K;                // N*K bytes
  float* asc = (float*)(w8 + (size_t)N * K);       // M floats
  float* wsc = asc + M;                            // N floats
  (void)ws_size; (void)n_in; (void)out_size;

  quant_all_kernel<<<M + N, 256, 0, stream>>>(x, w, x8, w8, asc, wsc, M, K);
  gemm_fp8_kernel<<<(M / BM) * (N / BN), 512, 0, stream>>>(x8, w8, asc, wsc, bias, out, M, N, K);
}

// Round 12
// 219.712 us; speedup vs baseline: 1.1056x; 1.1056x over previous
//
#include <hip/hip_runtime.h>
#include <hip/hip_fp16.h>
#include <stdint.h>

#define FP8_MAX_V 448.0f
#define BM 256
#define BN 128
#define BKB 128  // K-bytes per tile step (fp8 => 128 elements); LDS row = 128 B

typedef float floatx4 __attribute__((ext_vector_type(4)));
typedef int intx4 __attribute__((ext_vector_type(4)));
typedef int intx8 __attribute__((ext_vector_type(8)));

// asm wait/barrier with full compiler fencing (rule #18).
#define WAITVM(n)                                              \
  do {                                                         \
    asm volatile("s_waitcnt vmcnt(" #n ")" ::: "memory");      \
    __builtin_amdgcn_sched_barrier(0);                         \
  } while (0)
#define BARRIER()                                              \
  do {                                                         \
    __builtin_amdgcn_sched_barrier(0);                         \
    __builtin_amdgcn_s_barrier();                              \
    __builtin_amdgcn_sched_barrier(0);                         \
  } while (0)

// Deterministic bf16 round-to-nearest-even of an fp32 value, returned widened to fp32.
__device__ __forceinline__ float bf16_rne(float v) {
  uint32_t u = __float_as_uint(v);
  u = (u + 0x7fffu + ((u >> 16) & 1u)) & 0xffff0000u;
  return __uint_as_float(u);
}

// Pack 4 fp32 (already clipped to +-448) into 4 OCP e4m3fn bytes via HW RNE cvt.
__device__ __forceinline__ uint32_t pack4_fp8(float a, float b, float c, float d) {
  int p = 0;
  p = __builtin_amdgcn_cvt_pk_fp8_f32(a, b, p, false);  // bytes 0..1
  p = __builtin_amdgcn_cvt_pk_fp8_f32(c, d, p, true);   // bytes 2..3
  return (uint32_t)p;
}

__device__ __forceinline__ void gload_lds16(const uint8_t* g, uint8_t* l) {
  __builtin_amdgcn_global_load_lds(
      (const __attribute__((address_space(1))) uint32_t*)g,
      (__attribute__((address_space(3))) uint32_t*)l,
      16, 0, 0);
}

// Fused per-row quantization for BOTH x (blocks 0..M-1) and w (blocks M..M+N-1):
// amax over K -> scale -> fp8. Weight path fp16-round-trips the scale (matches
// reference's scale.astype(fp16).astype(fp32)).
__global__ __launch_bounds__(256) void quant_all_kernel(
    const float* __restrict__ x, const float* __restrict__ w,
    uint8_t* __restrict__ x8, uint8_t* __restrict__ w8,
    float* __restrict__ asc, float* __restrict__ wsc, int M, int K) {
  const int blk = blockIdx.x;
  const bool isW = blk >= M;
  const int row = isW ? (blk - M) : blk;
  const float* rp = (isW ? w : x) + (size_t)row * K;
  uint8_t* out8 = (isW ? w8 : x8) + (size_t)row * K;
  float* scp = (isW ? wsc : asc) + row;
  const int tid = threadIdx.x;

  // K = 4096: 16 floats/thread as 4x float4, coalesced (stride-256 float4s).
  float4 v[4];
  float amax = 0.f;
#pragma unroll
  for (int i = 0; i < 4; ++i) {
    v[i] = ((const float4*)rp)[i * 256 + tid];
    amax = fmaxf(amax, fmaxf(fmaxf(fabsf(v[i].x), fabsf(v[i].y)),
                             fmaxf(fabsf(v[i].z), fabsf(v[i].w))));
  }
#pragma unroll
  for (int off = 32; off; off >>= 1) amax = fmaxf(amax, __shfl_xor(amax, off));
  __shared__ float red[4];
  if ((tid & 63) == 0) red[tid >> 6] = amax;
  __syncthreads();
  amax = fmaxf(fmaxf(red[0], red[1]), fmaxf(red[2], red[3]));

  float scale = fmaxf(amax / FP8_MAX_V, 1e-6f);
  if (isW) scale = __half2float(__float2half(scale));  // RNE fp16 round-trip
  if (tid == 0) *scp = scale;

  uint32_t* op = (uint32_t*)out8;
#pragma unroll
  for (int i = 0; i < 4; ++i) {
    // true fp32 division (correctly rounded) to match numpy's x / scale
    float qa = fminf(fmaxf(v[i].x / scale, -FP8_MAX_V), FP8_MAX_V);
    float qb = fminf(fmaxf(v[i].y / scale, -FP8_MAX_V), FP8_MAX_V);
    float qc = fminf(fmaxf(v[i].z / scale, -FP8_MAX_V), FP8_MAX_V);
    float qd = fminf(fmaxf(v[i].w / scale, -FP8_MAX_V), FP8_MAX_V);
    op[i * 256 + tid] = pack4_fp8(qa, qb, qc, qd);
  }
}

// C[t,o] = sum_k A8[t,k]*B8[o,k]  (both K-major), scaled + bias + bf16 round.
// r7/r10 proven shell with the DS-traffic reduction of r8, at 2 blocks/CU:
//   BM=256 x BN=128 tile, 256 thr = 4 waves (2M x 2N), wave-tile 128x64 =
//   8x4 frags of mfma_scale_f32_16x16x128_f8f6f4 with UNIT scales (e8m0
//   0x7F = 1.0) -> fp8 e4m3 math at 2x rate. Wave-tile 128x64 cuts LDS
//   bytes/FLOP 1/64 -> 1/85 (DS-pipe floor ~62us ~= matrix floor ~59us).
//   A double-buffered (2 x 32 KB), B SINGLE-buffered (16 KB) = 80 KB LDS
//   exactly -> 2 blocks/CU (the r4/r8/r11 killer avoided).
// Compute (r8-proven): B-frags held in regs across both A-halves; every
// fragment ds_read exactly once (24 b128/wave/tile); compiler-scheduled.
//
// vmcnt ledger (per wave): prologue A(0)[8]+B(0)[4]+A(1)[8] = 20 in flight.
// Head of tile t: WAITVM(8) drains the 12 oldest = A(t)+B(t), keeps A(t+1).
// Tail (after the barrier ending tile t's reads): stageB(t+1)[4],
// stageA(t+2)[8] into the freed slots -> race-free by construction.
//
// LDS swizzle (T2, rule #21 both-sides): 16B chunk c16 within each 128B row
// XOR'd with (row&7); linear LDS dest (gload_lds) + pre-swizzled global
// source + swizzled read (fragment = chunks {2*hi, 2*hi+1} ^ (fr&7)).
// Measured at the 4 cyc/read b128 floor.
__global__ __launch_bounds__(256, 2) void gemm_fp8_kernel(
    const uint8_t* __restrict__ A8, const uint8_t* __restrict__ B8,
    const float* __restrict__ asc, const float* __restrict__ wsc,
    const float* __restrict__ bias, float* __restrict__ out,
    int M, int N, int K) {
  __shared__ __align__(16) uint8_t As[2][BM * BKB];  // 2 x 32 KB
  __shared__ __align__(16) uint8_t Bs[BN * BKB];     // 1 x 16 KB

  const int tid = threadIdx.x;
  const int lane = tid & 63;
  const int wid = tid >> 6;
  const int wr = wid >> 1;  // 0..1 (M dimension, 128 rows)
  const int wc = wid & 1;   // 0..1 (N dimension, 64 cols)

  const int ntn = N / BN;
  const int bm = blockIdx.x / ntn;
  const int bn = blockIdx.x % ntn;

  floatx4 acc[8][4] = {};

  // Staging: thread tid -> LDS linear offset tid*16 (row=tid>>3, c16=tid&7),
  // global source chunk = (tid&7) ^ (row&7). Row stride 32 between calls
  // preserves (row&7), so one source offset serves all calls.
  const int srow = tid >> 3;                      // 0..31
  const int sc_log = (tid & 7) ^ (srow & 7);      // pre-swizzled source chunk
  const uint8_t* gA = A8 + (size_t)(bm * BM + srow) * K + sc_log * 16;
  const uint8_t* gB = B8 + (size_t)(bn * BN + srow) * K + sc_log * 16;
  const size_t rstep = (size_t)32 * K;

  const int fr = lane & 15;        // fragment row/col within 16
  const int hi = lane >> 4;        // 0..3: K-block of 32 elems within the 128-tile
  const int fsw = fr & 7;          // read-side swizzle key
  // Lane's 32B fragment = chunks {2*hi, 2*hi+1}, each XOR-swizzled.
  const int cls = ((2 * hi) ^ fsw) * 16;      // low 16B chunk byte offset
  const int chs = ((2 * hi + 1) ^ fsw) * 16;  // high 16B chunk byte offset

  auto stageA = [&](int buf, int k0) {   // 256 rows x 128 B = 8 x 16B/thread
    uint8_t* lA = As[buf] + tid * 16;
#pragma unroll
    for (int i = 0; i < 8; ++i) gload_lds16(gA + i * rstep + k0, lA + i * 4096);
  };
  auto stageB = [&](int k0) {            // 128 rows x 128 B = 4 x 16B/thread
    uint8_t* lB = Bs + tid * 16;
#pragma unroll
    for (int i = 0; i < 4; ++i) gload_lds16(gB + i * rstep + k0, lB + i * 4096);
  };

  auto compute = [&](int buf) {
    const uint8_t* Ab = As[buf];
    intx8 b[4];
#pragma unroll
    for (int n = 0; n < 4; ++n) {
      const uint8_t* p = Bs + (size_t)(wc * 64 + n * 16 + fr) * BKB;
      intx4 lo = *(const intx4*)(p + cls);
      intx4 hh = *(const intx4*)(p + chs);
      b[n] = (intx8){lo.x, lo.y, lo.z, lo.w, hh.x, hh.y, hh.z, hh.w};
    }
#pragma unroll
    for (int mh = 0; mh < 2; ++mh) {
      intx8 a[4];
#pragma unroll
      for (int i = 0; i < 4; ++i) {
        const uint8_t* p = Ab + (size_t)(wr * 128 + (mh * 4 + i) * 16 + fr) * BKB;
        intx4 lo = *(const intx4*)(p + cls);
        intx4 hh = *(const intx4*)(p + chs);
        a[i] = (intx8){lo.x, lo.y, lo.z, lo.w, hh.x, hh.y, hh.z, hh.w};
      }
#pragma unroll
      for (int i = 0; i < 4; ++i)
#pragma unroll
        for (int n = 0; n < 4; ++n)
          // cbsz=0 (A=fp8 e4m3), blgp=0 (B=fp8 e4m3), scales = e8m0 0x7F = 1.0
          acc[mh * 4 + i][n] = __builtin_amdgcn_mfma_scale_f32_16x16x128_f8f6f4(
              a[i], b[n], acc[mh * 4 + i][n], 0, 0, 0, 0x7F7F7F7F, 0, 0x7F7F7F7F);
    }
  };

  const int NT = K / BKB;  // 32
  stageA(0, 0);    // 8
  stageB(0);       // 4
  stageA(1, BKB);  // 8  -> 20 in flight

  for (int t = 0; t < NT; ++t) {
    // Drain A(t)+B(t) (the 12 oldest); keep A(t+1)'s 8 in flight.
    if (t + 1 < NT) WAITVM(8); else WAITVM(0);
    BARRIER();   // all waves' tile-t data resident; Bs free of writers
    compute(t & 1);
    BARRIER();   // all waves done reading As[t&1] and Bs
    if (t + 1 < NT) stageB((t + 1) * BKB);           // oldest outstanding first
    if (t + 2 < NT) stageA(t & 1, (t + 2) * BKB);    // refill freed A buffer
  }

  // Epilogue: C/D 16x16 layout col=lane&15, row=(lane>>4)*4+r (dtype-independent;
  // f8f6f4-scaled C/D layout is shape-determined per m121-m128).
  const int rbase = bm * BM + wr * 128;
  const int cbase = bn * BN + wc * 64;
#pragma unroll
  for (int n = 0; n < 4; ++n) {
    const int col = cbase + n * 16 + fr;
    const float wv = wsc[col];
    const float bb = bf16_rne(bias[col]);  // bias.astype(bf16).astype(f32)
#pragma unroll
    for (int m = 0; m < 8; ++m) {
      const int r0 = rbase + m * 16 + hi * 4;
#pragma unroll
      for (int r = 0; r < 4; ++r) {
        const int row = r0 + r;
        // reference order: (acc * act_scale) * w_scale + bias_bf16, then bf16 RNE
        float v = (acc[m][n][r] * asc[row]) * wv + bb;
        out[(size_t)row * N + col] = bf16_rne(v);
      }
    }
  }
}

extern "C" void kernel_launch(void* const* d_in, const int* in_sizes, int n_in,
                              void* d_out, int out_size, void* d_ws, size_t ws_size,
                              hipStream_t stream) {
  const float* x = (const float*)d_in[0];     // [B,S,K] f32
  const float* w = (const float*)d_in[1];     // [N,K] f32
  const float* bias = (const float*)d_in[2];  // [N] f32
  float* out = (float*)d_out;                 // [M,N] f32 (bf16-rounded values)

  const int N = in_sizes[2];             // 4096 (D_OUT)
  const int K = in_sizes[1] / N;         // 4096 (D_IN)
  const int M = in_sizes[0] / K;         // 8192 tokens

  uint8_t* x8 = (uint8_t*)d_ws;                    // M*K bytes
  uint8_t* w8 = x8 + (size_t)M * K;                // N*K bytes
  float* asc = (float*)(w8 + (size_t)N * K);       // M floats
  float* wsc = asc + M;                            // N floats
  (void)ws_size; (void)n_in; (void)out_size;

  quant_all_kernel<<<M + N, 256, 0, stream>>>(x, w, x8, w8, asc, wsc, M, K);
  gemm_fp8_kernel<<<(M / BM) * (N / BN), 256, 0, stream>>>(x8, w8, asc, wsc, bias, out, M, N, K);
}

// Round 13
// 208.461 us; speedup vs baseline: 1.1652x; 1.0540x over previous
//
#include <hip/hip_runtime.h>
#include <hip/hip_fp16.h>
#include <stdint.h>

#define FP8_MAX_V 448.0f
#define BM 256
#define BN 256
#define BKB 128  // K-bytes per tile step (fp8 => 128 elements); LDS row = 128 B

typedef float floatx4 __attribute__((ext_vector_type(4)));
typedef int intx4 __attribute__((ext_vector_type(4)));
typedef int intx8 __attribute__((ext_vector_type(8)));

// asm wait/barrier with full compiler fencing (rule #18).
#define WAITVM(n)                                              \
  do {                                                         \
    asm volatile("s_waitcnt vmcnt(" #n ")" ::: "memory");      \
    __builtin_amdgcn_sched_barrier(0);                         \
  } while (0)
#define BARRIER()                                              \
  do {                                                         \
    __builtin_amdgcn_sched_barrier(0);                         \
    __builtin_amdgcn_s_barrier();                              \
    __builtin_amdgcn_sched_barrier(0);                         \
  } while (0)

// Deterministic bf16 round-to-nearest-even of an fp32 value, returned widened to fp32.
__device__ __forceinline__ float bf16_rne(float v) {
  uint32_t u = __float_as_uint(v);
  u = (u + 0x7fffu + ((u >> 16) & 1u)) & 0xffff0000u;
  return __uint_as_float(u);
}

// Pack 4 fp32 (already clipped to +-448) into 4 OCP e4m3fn bytes via HW RNE cvt.
__device__ __forceinline__ uint32_t pack4_fp8(float a, float b, float c, float d) {
  int p = 0;
  p = __builtin_amdgcn_cvt_pk_fp8_f32(a, b, p, false);  // bytes 0..1
  p = __builtin_amdgcn_cvt_pk_fp8_f32(c, d, p, true);   // bytes 2..3
  return (uint32_t)p;
}

__device__ __forceinline__ void gload_lds16(const uint8_t* g, uint8_t* l) {
  __builtin_amdgcn_global_load_lds(
      (const __attribute__((address_space(1))) uint32_t*)g,
      (__attribute__((address_space(3))) uint32_t*)l,
      16, 0, 0);
}

// Fused per-row quantization for BOTH x (blocks 0..M-1) and w (blocks M..M+N-1):
// amax over K -> scale -> fp8. Weight path fp16-round-trips the scale (matches
// reference's scale.astype(fp16).astype(fp32)).
__global__ __launch_bounds__(256) void quant_all_kernel(
    const float* __restrict__ x, const float* __restrict__ w,
    uint8_t* __restrict__ x8, uint8_t* __restrict__ w8,
    float* __restrict__ asc, float* __restrict__ wsc, int M, int K) {
  const int blk = blockIdx.x;
  const bool isW = blk >= M;
  const int row = isW ? (blk - M) : blk;
  const float* rp = (isW ? w : x) + (size_t)row * K;
  uint8_t* out8 = (isW ? w8 : x8) + (size_t)row * K;
  float* scp = (isW ? wsc : asc) + row;
  const int tid = threadIdx.x;

  // K = 4096: 16 floats/thread as 4x float4, coalesced (stride-256 float4s).
  float4 v[4];
  float amax = 0.f;
#pragma unroll
  for (int i = 0; i < 4; ++i) {
    v[i] = ((const float4*)rp)[i * 256 + tid];
    amax = fmaxf(amax, fmaxf(fmaxf(fabsf(v[i].x), fabsf(v[i].y)),
                             fmaxf(fabsf(v[i].z), fabsf(v[i].w))));
  }
#pragma unroll
  for (int off = 32; off; off >>= 1) amax = fmaxf(amax, __shfl_xor(amax, off));
  __shared__ float red[4];
  if ((tid & 63) == 0) red[tid >> 6] = amax;
  __syncthreads();
  amax = fmaxf(fmaxf(red[0], red[1]), fmaxf(red[2], red[3]));

  float scale = fmaxf(amax / FP8_MAX_V, 1e-6f);
  if (isW) scale = __half2float(__float2half(scale));  // RNE fp16 round-trip
  if (tid == 0) *scp = scale;

  uint32_t* op = (uint32_t*)out8;
#pragma unroll
  for (int i = 0; i < 4; ++i) {
    // true fp32 division (correctly rounded) to match numpy's x / scale
    float qa = fminf(fmaxf(v[i].x / scale, -FP8_MAX_V), FP8_MAX_V);
    float qb = fminf(fmaxf(v[i].y / scale, -FP8_MAX_V), FP8_MAX_V);
    float qc = fminf(fmaxf(v[i].z / scale, -FP8_MAX_V), FP8_MAX_V);
    float qd = fminf(fmaxf(v[i].w / scale, -FP8_MAX_V), FP8_MAX_V);
    op[i * 256 + tid] = pack4_fp8(qa, qb, qc, qd);
  }
}

// C[t,o] = sum_k A8[t,k]*B8[o,k]  (both K-major), scaled + bias + bf16 round.
// m201-style counted-vmcnt sub-tile schedule, fp8-MX port (both prior failure
// causes fixed: 128B-row fr&7 swizzle at the 4cyc floor, waits COUNTED never
// 0 in steady state):
//   256x256 tile, 512 thr = 8 waves (2M x 4N), wave-tile 128x64 = 8x4 frags
//   of mfma_scale_f32_16x16x128_f8f6f4 with UNIT scales (e8m0 0x7F = 1.0).
//   A,B double-buffered (4 x 32 KB = 128 KB LDS, 1 block/CU by design).
// Per K-tile, FOUR phases (phase p computes acc rows m=2p,2p+1 x all n;
// B-frags read once in ph0 and held in regs; a-frags 2 per phase; every
// fragment ds_read exactly once = 24 b128/wave/tile):
//   ph0: issue B1(t+1); WAITVM(4);  BARRIER; read b[4]+a(m0,m1); 8 MFMA
//   ph1: issue B2(t+1); (no wait/barrier)      read a(m2,m3);    8 MFMA
//   ph2: issue A1(t+1); WAITVM(6);  BARRIER;   read a(m4,m5);    8 MFMA
//   ph3: issue A2(t+1); (no wait/barrier)      read a(m6,m7);    8 MFMA
// Stage units (2 gloads each, issue order B1,B2,A1,A2): A1 = row-gloads
// {0,2} (rows 0-63,128-191 = m0..m3 for both wr), A2 = {1,3} (m4..m7).
// vmcnt ledger (steady): ph0 after issue = 10 outstanding -> WAITVM(4)
// drains B(t)+A1(t), keeps A2(t)+B1(t+1); ph2 after issue = 8 -> WAITVM(6)
// drains A2(t). Every unit gets >=2 phases (~1000 cyc) of latency cover;
// tail tile: ph0 WAITVM(2), ph2 WAITVM(0).
// Race-audit under max skew (bounded by the 2 block barriers): B[cur] last
// read ph0(t), overwrite issued ph0(t+1) which is behind ph2(t)'s barrier;
// A[cur] last read ph3(t), overwrite issued ph2(t+1) behind ph0(t+1)'s
// barrier -> safe.
__global__ __launch_bounds__(512, 2) void gemm_fp8_kernel(
    const uint8_t* __restrict__ A8, const uint8_t* __restrict__ B8,
    const float* __restrict__ asc, const float* __restrict__ wsc,
    const float* __restrict__ bias, float* __restrict__ out,
    int M, int N, int K) {
  __shared__ __align__(16) uint8_t As[2][BM * BKB];  // 2 x 32 KB
  __shared__ __align__(16) uint8_t Bs[2][BN * BKB];  // 2 x 32 KB

  const int tid = threadIdx.x;
  const int lane = tid & 63;
  const int wid = tid >> 6;
  const int wr = wid >> 2;  // 0..1 (M dimension, 128 rows)
  const int wc = wid & 3;   // 0..3 (N dimension, 64 cols)

  const int ntn = N / BN;
  const int bm = blockIdx.x / ntn;
  const int bn = blockIdx.x % ntn;

  floatx4 acc[8][4] = {};

  // Staging: thread tid -> LDS linear offset tid*16 (row=tid>>3, c16=tid&7),
  // global source chunk = (tid&7) ^ (row&7). Row stride 64 between gloads
  // preserves (row&7), so one source offset serves all.
  const int srow = tid >> 3;                      // 0..63
  const int sc_log = (tid & 7) ^ (srow & 7);      // pre-swizzled source chunk
  const uint8_t* gA = A8 + (size_t)(bm * BM + srow) * K + sc_log * 16;
  const uint8_t* gB = B8 + (size_t)(bn * BN + srow) * K + sc_log * 16;
  const size_t rstep = (size_t)64 * K;

  const int fr = lane & 15;        // fragment row/col within 16
  const int hi = lane >> 4;        // 0..3: K-block of 32 elems within the 128-tile
  const int fsw = fr & 7;          // read-side swizzle key
  // Lane's 32B fragment = chunks {2*hi, 2*hi+1}, each XOR-swizzled.
  const int cls = ((2 * hi) ^ fsw) * 16;      // low 16B chunk byte offset
  const int chs = ((2 * hi + 1) ^ fsw) * 16;  // high 16B chunk byte offset

  // Stage units: 2 gload_lds each. A rows gload i covers rows [64i, 64(i+1)).
  auto stageB1 = [&](int buf, int k0) {
    uint8_t* lB = Bs[buf] + tid * 16;
    gload_lds16(gB + 0 * rstep + k0, lB + 0 * 8192);
    gload_lds16(gB + 1 * rstep + k0, lB + 1 * 8192);
  };
  auto stageB2 = [&](int buf, int k0) {
    uint8_t* lB = Bs[buf] + tid * 16;
    gload_lds16(gB + 2 * rstep + k0, lB + 2 * 8192);
    gload_lds16(gB + 3 * rstep + k0, lB + 3 * 8192);
  };
  auto stageA1 = [&](int buf, int k0) {  // rows 0-63 & 128-191 (m0..m3, both wr)
    uint8_t* lA = As[buf] + tid * 16;
    gload_lds16(gA + 0 * rstep + k0, lA + 0 * 8192);
    gload_lds16(gA + 2 * rstep + k0, lA + 2 * 8192);
  };
  auto stageA2 = [&](int buf, int k0) {  // rows 64-127 & 192-255 (m4..m7)
    uint8_t* lA = As[buf] + tid * 16;
    gload_lds16(gA + 1 * rstep + k0, lA + 1 * 8192);
    gload_lds16(gA + 3 * rstep + k0, lA + 3 * 8192);
  };

  auto loadB = [&](intx8* b, int buf) {
#pragma unroll
    for (int n = 0; n < 4; ++n) {
      const uint8_t* p = Bs[buf] + (size_t)(wc * 64 + n * 16 + fr) * BKB;
      intx4 lo = *(const intx4*)(p + cls);
      intx4 hh = *(const intx4*)(p + chs);
      b[n] = (intx8){lo.x, lo.y, lo.z, lo.w, hh.x, hh.y, hh.z, hh.w};
    }
  };
  auto loadA2f = [&](intx8* a, int buf, int ph) {
#pragma unroll
    for (int j = 0; j < 2; ++j) {
      const uint8_t* p = As[buf] + (size_t)(wr * 128 + (2 * ph + j) * 16 + fr) * BKB;
      intx4 lo = *(const intx4*)(p + cls);
      intx4 hh = *(const intx4*)(p + chs);
      a[j] = (intx8){lo.x, lo.y, lo.z, lo.w, hh.x, hh.y, hh.z, hh.w};
    }
  };

#define MFMA8(ph, a, b)                                                       \
  do {                                                                        \
    __builtin_amdgcn_s_setprio(1);                                            \
    _Pragma("unroll") for (int j = 0; j < 2; ++j)                             \
        _Pragma("unroll") for (int n = 0; n < 4; ++n)                         \
        acc[2 * (ph) + j][n] = __builtin_amdgcn_mfma_scale_f32_16x16x128_f8f6f4( \
            (a)[j], (b)[n], acc[2 * (ph) + j][n], 0, 0, 0,                    \
            0x7F7F7F7F, 0, 0x7F7F7F7F);                                       \
    __builtin_amdgcn_s_setprio(0);                                            \
  } while (0)

  const int NT = K / BKB;  // 32
  // Prologue (issue order defines the vmcnt ledger): B1,B2,A1,A2 of tile 0.
  stageB1(0, 0); stageB2(0, 0); stageA1(0, 0); stageA2(0, 0);  // 8 in flight

  for (int t = 0; t < NT; ++t) {
    const int cur = t & 1, nxt = cur ^ 1;
    const int k1 = (t + 1) * BKB;
    intx8 b[4], a[2];

    // ---- ph0: needs B(t) + A1(t)
    if (t + 1 < NT) { stageB1(nxt, k1); WAITVM(4); } else { WAITVM(2); }
    BARRIER();
    loadB(b, cur);
    loadA2f(a, cur, 0);
    MFMA8(0, a, b);

    // ---- ph1: data already resident (A-unit-1)
    if (t + 1 < NT) stageB2(nxt, k1);
    loadA2f(a, cur, 1);
    MFMA8(1, a, b);

    // ---- ph2: needs A2(t)
    if (t + 1 < NT) { stageA1(nxt, k1); WAITVM(6); } else { WAITVM(0); }
    BARRIER();
    loadA2f(a, cur, 2);
    MFMA8(2, a, b);

    // ---- ph3: data already resident (A-unit-2)
    if (t + 1 < NT) stageA2(nxt, k1);
    loadA2f(a, cur, 3);
    MFMA8(3, a, b);
  }
#undef MFMA8

  // Epilogue: C/D 16x16 layout col=lane&15, row=(lane>>4)*4+r (dtype-independent;
  // f8f6f4-scaled C/D layout is shape-determined per m121-m128).
  const int rbase = bm * BM + wr * 128;
  const int cbase = bn * BN + wc * 64;
#pragma unroll
  for (int n = 0; n < 4; ++n) {
    const int col = cbase + n * 16 + fr;
    const float wv = wsc[col];
    const float bb = bf16_rne(bias[col]);  // bias.astype(bf16).astype(f32)
#pragma unroll
    for (int m = 0; m < 8; ++m) {
      const int r0 = rbase + m * 16 + hi * 4;
#pragma unroll
      for (int r = 0; r < 4; ++r) {
        const int row = r0 + r;
        // reference order: (acc * act_scale) * w_scale + bias_bf16, then bf16 RNE
        float v = (acc[m][n][r] * asc[row]) * wv + bb;
        out[(size_t)row * N + col] = bf16_rne(v);
      }
    }
  }
}

extern "C" void kernel_launch(void* const* d_in, const int* in_sizes, int n_in,
                              void* d_out, int out_size, void* d_ws, size_t ws_size,
                              hipStream_t stream) {
  const float* x = (const float*)d_in[0];     // [B,S,K] f32
  const float* w = (const float*)d_in[1];     // [N,K] f32
  const float* bias = (const float*)d_in[2];  // [N] f32
  float* out = (float*)d_out;                 // [M,N] f32 (bf16-rounded values)

  const int N = in_sizes[2];             // 4096 (D_OUT)
  const int K = in_sizes[1] / N;         // 4096 (D_IN)
  const int M = in_sizes[0] / K;         // 8192 tokens

  uint8_t* x8 = (uint8_t*)d_ws;                    // M*K bytes
  uint8_t* w8 = x8 + (size_t)M * K;                // N*K bytes
  float* asc = (float*)(w8 + (size_t)N * K);       // M floats
  float* wsc = asc + M;                            // N floats
  (void)ws_size; (void)n_in; (void)out_size;

  quant_all_kernel<<<M + N, 256, 0, stream>>>(x, w, x8, w8, asc, wsc, M, K);
  gemm_fp8_kernel<<<(M / BM) * (N / BN), 512, 0, stream>>>(x8, w8, asc, wsc, bias, out, M, N, K);
}